// Round 1
// baseline (385.070 us; speedup 1.0000x reference)
//
#include <hip/hip_runtime.h>
#include <math.h>

#define Bc 4
#define Lc 200
#define Hc 256
#define NHc 4
#define HSc 64
#define NBc 2
#define Mtot (Bc*Lc)   // 800 rows

static __device__ __forceinline__ float neg_fill() { return -4294967295.0f; } // -(2^32)+1

// ---------------- embedding + keep mask ----------------
__global__ void embed_k(const int* __restrict__ logs, const float* __restrict__ emb,
                        float* __restrict__ seqs) {
  int idx = blockIdx.x * 256 + threadIdx.x;      // Mtot*Hc threads total
  int hcol = idx & (Hc - 1);
  int bl = idx >> 8;                             // Hc==256
  int tok = logs[bl];
  seqs[idx] = (tok == 0) ? 0.f : emb[tok * Hc + hcol];
}

// ---------------- layernorm over H=256, one block per row ----------------
__global__ void ln_k(const float* __restrict__ x, const float* __restrict__ g,
                     const float* __restrict__ bt, float* __restrict__ y) {
  int row = blockIdx.x;
  int t = threadIdx.x;
  float v = x[row * Hc + t];
  float a = v, sq = v * v;
  for (int o = 32; o; o >>= 1) { a += __shfl_down(a, o); sq += __shfl_down(sq, o); }
  __shared__ float s1[4], s2[4];
  __shared__ float mS, rS;
  int wave = t >> 6, lane = t & 63;
  if (lane == 0) { s1[wave] = a; s2[wave] = sq; }
  __syncthreads();
  if (t == 0) {
    float sum = s1[0] + s1[1] + s1[2] + s1[3];
    float ssq = s2[0] + s2[1] + s2[2] + s2[3];
    float m = sum * (1.f / Hc);
    float var = ssq * (1.f / Hc) - m * m;
    mS = m;
    rS = 1.f / sqrtf(var + 1e-8f);
  }
  __syncthreads();
  y[row * Hc + t] = (v - mS) * rS * g[t] + bt[t];
}

// ---------------- GEMM: out[M,N] = A[M,K] @ W[N,K]^T + bias, small fusions ----
// FUSE: 0 = +bias ; 1 = relu(+bias) ; 2 = (+bias + X) * keep(logs)
template <int FUSE>
__global__ void gemm_k(const float* __restrict__ A, const float* __restrict__ W,
                       const float* __restrict__ bias, const float* __restrict__ X,
                       const int* __restrict__ logs, float* __restrict__ out) {
  __shared__ float As[32][33];
  __shared__ float Ws[32][33];
  int m0 = blockIdx.x * 32, n0 = blockIdx.y * 32;
  int t = threadIdx.x;                 // 256 threads
  int tx = t & 15, ty = t >> 4;        // 16x16, 2x2 micro-tile
  int lr = t >> 3, lc = (t & 7) * 4;   // staging: 32 rows x 8 float4
  float c00 = 0.f, c01 = 0.f, c10 = 0.f, c11 = 0.f;
  for (int k0 = 0; k0 < Hc; k0 += 32) {
    float4 av = *(const float4*)&A[(m0 + lr) * Hc + k0 + lc];
    float4 wv = *(const float4*)&W[(n0 + lr) * Hc + k0 + lc];
    As[lr][lc] = av.x; As[lr][lc + 1] = av.y; As[lr][lc + 2] = av.z; As[lr][lc + 3] = av.w;
    Ws[lr][lc] = wv.x; Ws[lr][lc + 1] = wv.y; Ws[lr][lc + 2] = wv.z; Ws[lr][lc + 3] = wv.w;
    __syncthreads();
#pragma unroll
    for (int k = 0; k < 32; ++k) {
      float a0 = As[2 * ty][k], a1 = As[2 * ty + 1][k];
      float w0 = Ws[2 * tx][k], w1 = Ws[2 * tx + 1][k];
      c00 += a0 * w0; c01 += a0 * w1; c10 += a1 * w0; c11 += a1 * w1;
    }
    __syncthreads();
  }
  int m = m0 + 2 * ty, n = n0 + 2 * tx;
  float b0 = bias[n], b1v = bias[n + 1];
  float r00 = c00 + b0, r01 = c01 + b1v, r10 = c10 + b0, r11 = c11 + b1v;
  if (FUSE == 1) {
    r00 = fmaxf(r00, 0.f); r01 = fmaxf(r01, 0.f);
    r10 = fmaxf(r10, 0.f); r11 = fmaxf(r11, 0.f);
  } else if (FUSE == 2) {
    float k0m = (logs[m] != 0) ? 1.f : 0.f;
    float k1m = (logs[m + 1] != 0) ? 1.f : 0.f;
    r00 = (r00 + X[m * Hc + n]) * k0m;
    r01 = (r01 + X[m * Hc + n + 1]) * k0m;
    r10 = (r10 + X[(m + 1) * Hc + n]) * k1m;
    r11 = (r11 + X[(m + 1) * Hc + n + 1]) * k1m;
  }
  out[m * Hc + n] = r00; out[m * Hc + n + 1] = r01;
  out[(m + 1) * Hc + n] = r10; out[(m + 1) * Hc + n + 1] = r11;
}

// ---------------- fused relative attention + residual ----------------
// one block per (b,q); wave h handles head h
__global__ void attn_k(const float* __restrict__ Q, const float* __restrict__ K,
                       const float* __restrict__ V,
                       const float* __restrict__ pK, const float* __restrict__ pV,
                       const float* __restrict__ tK, const float* __restrict__ tV,
                       const float* __restrict__ dK, const float* __restrict__ dV,
                       const int* __restrict__ tm, const int* __restrict__ dm,
                       const int* __restrict__ logs,
                       const float* __restrict__ Qn, float* __restrict__ seqs) {
  int bq = blockIdx.x;
  int b = bq / Lc, q = bq - b * Lc;
  int t = threadIdx.x, h = t >> 6, lane = t & 63;
  __shared__ float sQ[Hc];
  __shared__ float sS[NHc][Lc];
  __shared__ int sTM[Lc], sDM[Lc], sPad[Lc];
  sQ[t] = Q[bq * Hc + t];
  if (t < Lc) {
    sTM[t] = tm[bq * Lc + t];
    sDM[t] = dm[bq * Lc + t];
    sPad[t] = (logs[b * Lc + t] == 0);
  }
  __syncthreads();
  const float* Qh = &sQ[h * HSc];
  // scores: lane owns key index k (strided)
  for (int k = lane; k < Lc; k += 64) {
    const float* Kr = &K[(b * Lc + k) * Hc + h * HSc];
    const float* pKr = &pK[k * Hc + h * HSc];
    const float* tKr = &tK[sTM[k] * Hc + h * HSc];
    const float* dKr = &dK[sDM[k] * Hc + h * HSc];
    float acc = 0.f;
#pragma unroll 16
    for (int d = 0; d < HSc; ++d)
      acc += Qh[d] * (Kr[d] + pKr[d] + tKr[d] + dKr[d]);
    bool masked = (k > q) || (sPad[k] != 0);
    sS[h][k] = masked ? neg_fill() : acc * 0.125f;   // /sqrt(64)
  }
  // wave softmax over 200 keys
  float mx = -INFINITY;
  for (int k = lane; k < Lc; k += 64) mx = fmaxf(mx, sS[h][k]);
  for (int o = 32; o; o >>= 1) mx = fmaxf(mx, __shfl_xor(mx, o));
  float sum = 0.f;
  for (int k = lane; k < Lc; k += 64) {
    float e = expf(sS[h][k] - mx);
    sS[h][k] = e;
    sum += e;
  }
  for (int o = 32; o; o >>= 1) sum += __shfl_xor(sum, o);
  float rsum = 1.f / sum;
  // output: lane owns d
  float acc = 0.f;
  for (int k = 0; k < Lc; ++k) {
    float a = sS[h][k];
    acc += a * (V[(b * Lc + k) * Hc + h * HSc + lane]
              + pV[k * Hc + h * HSc + lane]
              + tV[sTM[k] * Hc + h * HSc + lane]
              + dV[sDM[k] * Hc + h * HSc + lane]);
  }
  int oi = bq * Hc + h * HSc + lane;
  seqs[oi] = Qn[oi] + acc * rsum;   // residual from LN1 output
}

extern "C" void kernel_launch(void* const* d_in, const int* in_sizes, int n_in,
                              void* d_out, int out_size, void* d_ws, size_t ws_size,
                              hipStream_t stream) {
  const int* logs = (const int*)d_in[0];
  const int* tm   = (const int*)d_in[1];
  const int* dm   = (const int*)d_in[2];
  const float* item = (const float*)d_in[3];
  const float* pK = (const float*)d_in[4];
  const float* pV = (const float*)d_in[5];
  const float* tK = (const float*)d_in[6];
  const float* tV = (const float*)d_in[7];
  const float* dK = (const float*)d_in[8];
  const float* dV = (const float*)d_in[9];
  const float* ln1_g = (const float*)d_in[10];
  const float* ln1_b = (const float*)d_in[11];
  const float* Wq = (const float*)d_in[12];
  const float* bq = (const float*)d_in[13];
  const float* Wk = (const float*)d_in[14];
  const float* bk = (const float*)d_in[15];
  const float* Wv = (const float*)d_in[16];
  const float* bv = (const float*)d_in[17];
  const float* ln2_g = (const float*)d_in[18];
  const float* ln2_b = (const float*)d_in[19];
  const float* W1 = (const float*)d_in[20];
  const float* b1 = (const float*)d_in[21];
  const float* W2 = (const float*)d_in[22];
  const float* b2 = (const float*)d_in[23];
  const float* lnf_g = (const float*)d_in[24];
  const float* lnf_b = (const float*)d_in[25];

  const int NROW = Mtot * Hc;          // 204800 floats per activation buffer
  float* ws = (float*)d_ws;
  float* sSeqs = ws + 0 * NROW;
  float* sQn   = ws + 1 * NROW;
  float* sQ    = ws + 2 * NROW;
  float* sK    = ws + 3 * NROW;
  float* sV    = ws + 4 * NROW;
  float* sX    = ws + 5 * NROW;
  float* sH    = ws + 6 * NROW;

  embed_k<<<NROW / 256, 256, 0, stream>>>(logs, item, sSeqs);

  dim3 gg(Mtot / 32, Hc / 32);
  for (int i = 0; i < NBc; ++i) {
    ln_k<<<Mtot, Hc, 0, stream>>>(sSeqs, ln1_g + i * Hc, ln1_b + i * Hc, sQn);
    gemm_k<0><<<gg, 256, 0, stream>>>(sQn,   Wq + i * Hc * Hc, bq + i * Hc, nullptr, nullptr, sQ);
    gemm_k<0><<<gg, 256, 0, stream>>>(sSeqs, Wk + i * Hc * Hc, bk + i * Hc, nullptr, nullptr, sK);
    gemm_k<0><<<gg, 256, 0, stream>>>(sSeqs, Wv + i * Hc * Hc, bv + i * Hc, nullptr, nullptr, sV);
    attn_k<<<Mtot, 256, 0, stream>>>(sQ, sK, sV, pK, pV, tK, tV, dK, dV, tm, dm, logs, sQn, sSeqs);
    ln_k<<<Mtot, Hc, 0, stream>>>(sSeqs, ln2_g + i * Hc, ln2_b + i * Hc, sX);
    gemm_k<1><<<gg, 256, 0, stream>>>(sX, W1 + i * Hc * Hc, b1 + i * Hc, nullptr, nullptr, sH);
    gemm_k<2><<<gg, 256, 0, stream>>>(sH, W2 + i * Hc * Hc, b2 + i * Hc, sX, logs, sSeqs);
  }
  ln_k<<<Mtot, Hc, 0, stream>>>(sSeqs, lnf_g, lnf_b, (float*)d_out);
}